// Round 10
// baseline (174.684 us; speedup 1.0000x reference)
//
#include <hip/hip_runtime.h>

#define T_STEPS 200
#define IN_DIM 1086
#define KTILES 34              // K padded to 1088
#define M_TOTAL 51200          // 256*200

using f32x4v  = __attribute__((ext_vector_type(4))) float;
using bf16x8  = __attribute__((ext_vector_type(8))) short;
using u32x4   = __attribute__((ext_vector_type(4))) unsigned int;
typedef unsigned uv2 __attribute__((ext_vector_type(2)));

#if __has_builtin(__builtin_amdgcn_permlane16_swap) && __has_builtin(__builtin_amdgcn_permlane32_swap)
#define HAVE_PERMLANE_SWAP 1
#else
#define HAVE_PERMLANE_SWAP 0
#endif

#if __has_builtin(__builtin_amdgcn_exp2f)
#define EXP2F(x) __builtin_amdgcn_exp2f(x)
#else
#define EXP2F(x) exp2f(x)
#endif

// global_load_lds: per-lane GLOBAL source, wave-uniform LDS base + lane*size.
#define GLDS(gp, lp, sz) __builtin_amdgcn_global_load_lds(                         \
    (const __attribute__((address_space(1))) unsigned int*)(gp),                   \
    (__attribute__((address_space(3))) unsigned int*)(lp), sz, 0, 0)

__device__ __forceinline__ float rl_f(float v, int lane) {
    return __uint_as_float((unsigned)__builtin_amdgcn_readlane((int)__float_as_uint(v), lane));
}

// ---------------------------------------------------------------------------
// prepack_w: W_ih0[64][1086] fp32 -> hi/lo bf16, frag layout [kt][kg][64][8],
// zero-padded to K=1088 (A-tail garbage multiplies by 0). L2-resident.
// ---------------------------------------------------------------------------
__global__ __launch_bounds__(256) void prepack_w(
    const float* __restrict__ W,
    unsigned short* __restrict__ Wh, unsigned short* __restrict__ Wl)
{
    int idx = blockIdx.x * 256 + threadIdx.x;
    if (idx >= KTILES * 4 * 64 * 8) return;
    int j = idx & 7;
    int n = (idx >> 3) & 63;
    int k = (idx >> 9) * 8 + j;
    float v = (k < IN_DIM) ? W[n * IN_DIM + k] : 0.0f;
    unsigned u = __float_as_uint(v);
    unsigned hi = u & 0xffff0000u;
    float lo = v - __uint_as_float(hi);
    Wh[idx] = (unsigned short)(u >> 16);
    Wl[idx] = (unsigned short)(__float_as_uint(lo) >> 16);
}

__device__ __forceinline__ void cvt_hilo(const float (&a)[8], bf16x8& hv, bf16x8& lv) {
    union { u32x4 u; bf16x8 v; } H, L;
    #pragma unroll
    for (int p = 0; p < 4; ++p) {
        float a0 = a[2 * p], a1 = a[2 * p + 1];
        unsigned u0 = __float_as_uint(a0), u1 = __float_as_uint(a1);
        unsigned h0 = u0 & 0xffff0000u, h1 = u1 & 0xffff0000u;
        H.u[p] = (u0 >> 16) | h1;
        float l0 = a0 - __uint_as_float(h0);
        float l1 = a1 - __uint_as_float(h1);
        L.u[p] = (__float_as_uint(l0) >> 16) | (__float_as_uint(l1) & 0xffff0000u);
    }
    hv = H.v; lv = L.v;
}

// ---------------------------------------------------------------------------
// pre0_gemm_v6: v5 addressing verbatim (absmax-0 verified), sync restructured
// per T3/T4: 3 LDS buffers, raw s_barrier + COUNTED s_waitcnt vmcnt(N) —
// never vmcnt(0) in the main loop, so each tile's 10 loads/thread stay in
// flight for ~2 iterations (>= HBM latency). __syncthreads (vmcnt(0) drain
// every iter) was the ~2TB/s wall across R4-R9.
// Iter i: fire F(i+2) -> vmcnt(20) [F(i) done; F(i+1),F(i+2) flying]
//         -> s_barrier -> compute C(i).
// ---------------------------------------------------------------------------
__global__ __launch_bounds__(256) void pre0_gemm_v6(
    const float* __restrict__ X,
    const unsigned short* __restrict__ Wh, const unsigned short* __restrict__ Wl,
    const float* __restrict__ bias, float* __restrict__ out)
{
    __shared__ float          As[3][2048];      // 24KB
    __shared__ unsigned short Bs[3][2][2048];   // 24KB

    const int tid  = threadIdx.x;
    const int lane = tid & 63;
    const int wv   = tid >> 6;
    const int fr   = lane & 15;
    const int kg   = lane >> 4;
    const long m0  = (long)blockIdx.x * 64;

    // ---- staging geometry (per lane): inst i covers row rbase+2i (half-wave pair)
    const int rbase = wv * 16 + (lane >> 5);
    const int sidx  = (lane >> 2) & 7;
    const int dsub  = lane & 3;
    int koff[8];                                   // k-byte offset per inst (XOR-swizzled)
    #pragma unroll
    for (int i = 0; i < 8; ++i)
        koff[i] = ((sidx ^ ((rbase + 2 * i) & 7)) * 4 + dsub) * 4;
    const char* Xrow = (const char*)X + (m0 + rbase) * 4344;

    f32x4v acc[4];
    #pragma unroll
    for (int nf = 0; nf < 4; ++nf)
        #pragma unroll
        for (int r = 0; r < 4; ++r) acc[nf][r] = 0.0f;

    // fire tile kt into buffer bf (10 glds/thread; tail k>=1086 clamped, W pad=0)
    auto fire = [&](int kt, int bf) {
        const int kb = kt * 128;
        #pragma unroll
        for (int i = 0; i < 8; ++i) {
            int off = kb + koff[i];
            off = off > 4340 ? 4340 : off;
            GLDS(Xrow + (long)i * 8688 + off, &As[bf][wv * 512 + i * 64], 4);
        }
        GLDS(Wh + (size_t)kt * 2048 + tid * 8, (char*)Bs[bf][0] + wv * 1024, 16);
        GLDS(Wl + (size_t)kt * 2048 + tid * 8, (char*)Bs[bf][1] + wv * 1024, 16);
    };
    // compute tile from buffer cur
    auto compute = [&](int cur) {
        const int r  = wv * 16 + fr;
        const int r7 = r & 7;
        const float* pa1 = &As[cur][r * 32 + (((2 * kg) ^ r7) << 2)];
        const float* pa2 = &As[cur][r * 32 + ((((2 * kg) | 1) ^ r7) << 2)];
        float a[8];
        *(f32x4v*)&a[0] = *(const f32x4v*)pa1;
        *(f32x4v*)&a[4] = *(const f32x4v*)pa2;
        bf16x8 ah, al;
        cvt_hilo(a, ah, al);
        #pragma unroll
        for (int nf = 0; nf < 4; ++nf) {
            const int bofs = (kg * 64 + nf * 16 + fr) * 8;
            bf16x8 bh = *(const bf16x8*)&Bs[cur][0][bofs];
            bf16x8 bl = *(const bf16x8*)&Bs[cur][1][bofs];
            acc[nf] = __builtin_amdgcn_mfma_f32_16x16x32_bf16(ah, bh, acc[nf], 0, 0, 0);
            acc[nf] = __builtin_amdgcn_mfma_f32_16x16x32_bf16(al, bh, acc[nf], 0, 0, 0);
            acc[nf] = __builtin_amdgcn_mfma_f32_16x16x32_bf16(ah, bl, acc[nf], 0, 0, 0);
        }
    };

    // ---- prologue: 2 tiles in flight
    fire(0, 0);
    fire(1, 1);

    // ---- main loop: i = 0..31  (F(i+1),F(i+2) stay in flight across barrier)
    for (int i = 0; i < KTILES - 2; ++i) {
        fire(i + 2, (i + 2) % 3);
        asm volatile("s_waitcnt vmcnt(20)" ::: "memory");   // F(i) complete
        __builtin_amdgcn_s_barrier();                       // raw: no drain
        __builtin_amdgcn_sched_barrier(0);
        compute(i % 3);
    }
    // ---- peeled tail: i = 32, 33
    asm volatile("s_waitcnt vmcnt(10)" ::: "memory");       // F(32) complete
    __builtin_amdgcn_s_barrier();
    __builtin_amdgcn_sched_barrier(0);
    compute((KTILES - 2) % 3);
    asm volatile("s_waitcnt vmcnt(0)" ::: "memory");        // F(33) complete
    __builtin_amdgcn_s_barrier();
    __builtin_amdgcn_sched_barrier(0);
    compute((KTILES - 1) % 3);

    // ---- epilogue: +bias, fp32 store. C/D map: col=lane&15, row=(lane>>4)*4+r
    float bvv[4];
    #pragma unroll
    for (int nf = 0; nf < 4; ++nf) bvv[nf] = bias[nf * 16 + fr];
    #pragma unroll
    for (int nf = 0; nf < 4; ++nf)
        #pragma unroll
        for (int rr = 0; rr < 4; ++rr) {
            long row = m0 + wv * 16 + kg * 4 + rr;
            out[row * 64 + nf * 16 + fr] = acc[nf][rr] + bvv[nf];
        }
}

// ---------------------------------------------------------------------------
// mega_scan: 4-wave layer pipeline (unchanged — ~45us).
// ---------------------------------------------------------------------------
__global__ __launch_bounds__(256) void mega_scan(
    const float* __restrict__ pre0, const float* __restrict__ whh0,
    const float* __restrict__ wih1, const float* __restrict__ whh1, const float* __restrict__ b1,
    const float* __restrict__ wih2, const float* __restrict__ whh2, const float* __restrict__ b2,
    const float* __restrict__ wih3, const float* __restrict__ whh3, const float* __restrict__ b3,
    const float* __restrict__ w_fc1, const float* __restrict__ b_fc1,
    const float* __restrict__ w_fc2, const float* __restrict__ b_fc2,
    float* __restrict__ out)
{
    __shared__ float buf[3][T_STEPS][16];

    const int b    = blockIdx.x;
    const int tid  = threadIdx.x;
    const int g    = tid & 63;
    const int wv   = tid >> 6;

    bool sel16 = false, sel32 = false;
#if HAVE_PERMLANE_SWAP
    {
        uv2 q16 = __builtin_amdgcn_permlane16_swap((unsigned)g, (unsigned)g, false, false);
        sel16 = (__builtin_amdgcn_readfirstlane((int)q16[1]) == 16);
        uv2 q32 = __builtin_amdgcn_permlane32_swap((unsigned)g, (unsigned)g, false, false);
        sel32 = (__builtin_amdgcn_readfirstlane((int)q32[1]) == 32);
    }
#endif

    const float* wih = nullptr; const float* whh; const float* bias = nullptr;
    if      (wv == 0) { whh = whh0; }
    else if (wv == 1) { wih = wih1; whh = whh1; bias = b1; }
    else if (wv == 2) { wih = wih2; whh = whh2; bias = b2; }
    else              { wih = wih3; whh = whh3; bias = b3; }

    float whh_r[16];
    #pragma unroll
    for (int q = 0; q < 4; ++q)
        *(float4*)&whh_r[q * 4] = *(const float4*)&whh[g * 16 + q * 4];
    float wih_r[16]; float bg = 0.0f;
    if (wv) {
        #pragma unroll
        for (int q = 0; q < 4; ++q)
            *(float4*)&wih_r[q * 4] = *(const float4*)&wih[g * 16 + q * 4];
        bg = bias[g];
    }

    const float* pb = pre0 + (size_t)b * T_STEPS * 64 + g;
    float pc = 0.0f, p1 = 0.0f, p2 = 0.0f;
    if (wv == 0) { pc = pb[0]; p1 = pb[64]; p2 = pb[128]; }

    float hs[16];
    #pragma unroll
    for (int k = 0; k < 16; ++k) hs[k] = 0.0f;
    float c = 0.0f;

    const int q4 = g >> 4;
    const float escale = (q4 == 2) ? -2.8853900817779268f : -1.4426950408889634f;
    const float am = (q4 == 2) ? 2.0f : 1.0f;
    const float aa = (q4 == 2) ? -1.0f : 0.0f;

    for (int tau = 0; tau < T_STEPS + 3; ++tau) {
        __syncthreads();
        const int t = tau - wv;
        if (t >= 0 && t < T_STEPS) {
            float xr[16];
            if (wv) {
                #pragma unroll
                for (int q = 0; q < 4; ++q)
                    *(float4*)&xr[q * 4] = *(const float4*)&buf[wv - 1][t][q * 4];
            }
            float r0 = fmaf(whh_r[0], hs[0], wv ? bg : pc);
            float r1 = whh_r[1] * hs[1];
            float r2 = whh_r[2] * hs[2];
            float r3 = whh_r[3] * hs[3];
            #pragma unroll
            for (int k = 4; k < 16; k += 4) {
                r0 = fmaf(whh_r[k + 0], hs[k + 0], r0);
                r1 = fmaf(whh_r[k + 1], hs[k + 1], r1);
                r2 = fmaf(whh_r[k + 2], hs[k + 2], r2);
                r3 = fmaf(whh_r[k + 3], hs[k + 3], r3);
            }
            float acc = (r0 + r1) + (r2 + r3);
            if (wv) {
                float p0 = wih_r[0] * xr[0];
                float q1 = wih_r[1] * xr[1];
                float q2 = wih_r[2] * xr[2];
                float q3 = wih_r[3] * xr[3];
                #pragma unroll
                for (int k = 4; k < 16; k += 4) {
                    p0 = fmaf(wih_r[k + 0], xr[k + 0], p0);
                    q1 = fmaf(wih_r[k + 1], xr[k + 1], q1);
                    q2 = fmaf(wih_r[k + 2], xr[k + 2], q2);
                    q3 = fmaf(wih_r[k + 3], xr[k + 3], q3);
                }
                acc += (p0 + q1) + (q2 + q3);
            }
            float e = EXP2F(escale * acc);
            float s = __builtin_amdgcn_rcpf(1.0f + e);
            float a = fmaf(am, s, aa);
#if HAVE_PERMLANE_SWAP
            unsigned au = __float_as_uint(a);
            uv2 r16 = __builtin_amdgcn_permlane16_swap(au, au, false, false);
            uv2 r32 = __builtin_amdgcn_permlane32_swap(au, au, false, false);
            unsigned fvu = sel16 ? r16[1] : r16[0];
            unsigned gvu = sel32 ? r32[1] : r32[0];
            uv2 r48 = __builtin_amdgcn_permlane16_swap(gvu, gvu, false, false);
            unsigned ovu = sel16 ? r48[1] : r48[0];
            float fv = __uint_as_float(fvu);
            float gv = __uint_as_float(gvu);
            float ov = __uint_as_float(ovu);
#else
            float fv = __shfl_xor(a, 16, 64);
            float gv = __shfl_xor(a, 32, 64);
            float ov = __shfl_xor(a, 48, 64);
#endif
            c = fmaf(fv, c, a * gv);
            float e2 = EXP2F(-2.8853900817779268f * c);
            float s2 = __builtin_amdgcn_rcpf(1.0f + e2);
            float hn = fmaf(ov + ov, s2, -ov);
            if (wv < 3 && g < 16) buf[wv][t][g] = hn;
            #pragma unroll
            for (int k = 0; k < 16; ++k) hs[k] = rl_f(hn, k);
            if (wv == 0) {
                pc = p1; p1 = p2;
                int tn = t + 3; tn = tn < T_STEPS ? tn : T_STEPS - 1;
                p2 = pb[(size_t)tn * 64];
            }
        }
    }

    if (wv == 3 && g < 16) {
        float a1 = b_fc1[g];
        #pragma unroll
        for (int k = 0; k < 16; ++k) a1 = fmaf(w_fc1[g * 16 + k], hs[k], a1);
        a1 = fmaxf(a1, 0.0f);
        float h1[16];
        #pragma unroll
        for (int k = 0; k < 16; ++k) h1[k] = rl_f(a1, k);
        float lg = -3.0e38f;
        if (g < 15) {
            lg = b_fc2[g];
            #pragma unroll
            for (int k = 0; k < 16; ++k) lg = fmaf(w_fc2[g * 16 + k], h1[k], lg);
        }
        float mx = lg;
        #pragma unroll
        for (int d = 8; d >= 1; d >>= 1) mx = fmaxf(mx, __shfl_xor(mx, d, 16));
        float ev = (g < 15) ? EXP2F(1.4426950408889634f * (lg - mx)) : 0.0f;
        float sm = ev;
        #pragma unroll
        for (int d = 8; d >= 1; d >>= 1) sm += __shfl_xor(sm, d, 16);
        if (g < 15) out[b * 15 + g] = ev * __builtin_amdgcn_rcpf(sm);
    }
}

extern "C" void kernel_launch(void* const* d_in, const int* in_sizes, int n_in,
                              void* d_out, int out_size, void* d_ws, size_t ws_size,
                              hipStream_t stream) {
    const float* x    = (const float*)d_in[0];
    const float* wih0 = (const float*)d_in[1];
    const float* whh0 = (const float*)d_in[2];
    const float* b0   = (const float*)d_in[3];
    const float* wih1 = (const float*)d_in[4];
    const float* whh1 = (const float*)d_in[5];
    const float* b1   = (const float*)d_in[6];
    const float* wih2 = (const float*)d_in[7];
    const float* whh2 = (const float*)d_in[8];
    const float* b2   = (const float*)d_in[9];
    const float* wih3 = (const float*)d_in[10];
    const float* whh3 = (const float*)d_in[11];
    const float* b3   = (const float*)d_in[12];
    const float* wfc1 = (const float*)d_in[13];
    const float* bfc1 = (const float*)d_in[14];
    const float* wfc2 = (const float*)d_in[15];
    const float* bfc2 = (const float*)d_in[16];

    float* pre0 = (float*)d_ws;                                       // 13,107,200 B
    unsigned short* Wh = (unsigned short*)((char*)d_ws + 13107200);   // 139,264 B
    unsigned short* Wl = (unsigned short*)((char*)d_ws + 13107200 + 139264);

    prepack_w<<<dim3((KTILES * 4 * 64 * 8 + 255) / 256), dim3(256), 0, stream>>>(wih0, Wh, Wl);
    pre0_gemm_v6<<<dim3(M_TOTAL / 64), dim3(256), 0, stream>>>(x, Wh, Wl, b0, pre0);
    mega_scan<<<dim3(256), dim3(256), 0, stream>>>(pre0, whh0,
        wih1, whh1, b1, wih2, whh2, b2, wih3, whh3, b3,
        wfc1, bfc1, wfc2, bfc2, (float*)d_out);
}

// Round 11
// 161.648 us; speedup vs baseline: 1.0806x; 1.0806x over previous
//
#include <hip/hip_runtime.h>

#define T_STEPS 200
#define IN_DIM 1086
#define KTILES 34              // K padded to 1088
#define M_TOTAL 51200          // 256*200

using f32x4v  = __attribute__((ext_vector_type(4))) float;
using bf16x8  = __attribute__((ext_vector_type(8))) short;
using u32x4   = __attribute__((ext_vector_type(4))) unsigned int;
typedef unsigned uv2 __attribute__((ext_vector_type(2)));

#if __has_builtin(__builtin_amdgcn_permlane16_swap) && __has_builtin(__builtin_amdgcn_permlane32_swap)
#define HAVE_PERMLANE_SWAP 1
#else
#define HAVE_PERMLANE_SWAP 0
#endif

#if __has_builtin(__builtin_amdgcn_exp2f)
#define EXP2F(x) __builtin_amdgcn_exp2f(x)
#else
#define EXP2F(x) exp2f(x)
#endif

// global_load_lds: per-lane GLOBAL source, wave-uniform LDS base + lane*size.
#define GLDS(gp, lp, sz) __builtin_amdgcn_global_load_lds(                         \
    (const __attribute__((address_space(1))) unsigned int*)(gp),                   \
    (__attribute__((address_space(3))) unsigned int*)(lp), sz, 0, 0)

// inline-asm LDS read: compiler cannot see the LDS dependency -> cannot insert
// its own vmcnt(0) drain; correctness provided by counted vmcnt + barriers.
#define DSR(dst, addr, off) \
    asm volatile("ds_read_b128 %0, %1 offset:%2" : "=v"(dst) : "v"(addr), "n"(off))

__device__ __forceinline__ float rl_f(float v, int lane) {
    return __uint_as_float((unsigned)__builtin_amdgcn_readlane((int)__float_as_uint(v), lane));
}

// ---------------------------------------------------------------------------
// prepack_w: W_ih0[64][1086] fp32 -> hi/lo bf16, frag layout [kt][kg][64][8],
// zero-padded to K=1088 (A-tail garbage multiplies by 0). L2-resident.
// ---------------------------------------------------------------------------
__global__ __launch_bounds__(256) void prepack_w(
    const float* __restrict__ W,
    unsigned short* __restrict__ Wh, unsigned short* __restrict__ Wl)
{
    int idx = blockIdx.x * 256 + threadIdx.x;
    if (idx >= KTILES * 4 * 64 * 8) return;
    int j = idx & 7;
    int n = (idx >> 3) & 63;
    int k = (idx >> 9) * 8 + j;
    float v = (k < IN_DIM) ? W[n * IN_DIM + k] : 0.0f;
    unsigned u = __float_as_uint(v);
    unsigned hi = u & 0xffff0000u;
    float lo = v - __uint_as_float(hi);
    Wh[idx] = (unsigned short)(u >> 16);
    Wl[idx] = (unsigned short)(__float_as_uint(lo) >> 16);
}

__device__ __forceinline__ void cvt_hilo(const float (&a)[8], bf16x8& hv, bf16x8& lv) {
    union { u32x4 u; bf16x8 v; } H, L;
    #pragma unroll
    for (int p = 0; p < 4; ++p) {
        float a0 = a[2 * p], a1 = a[2 * p + 1];
        unsigned u0 = __float_as_uint(a0), u1 = __float_as_uint(a1);
        unsigned h0 = u0 & 0xffff0000u, h1 = u1 & 0xffff0000u;
        H.u[p] = (u0 >> 16) | h1;
        float l0 = a0 - __uint_as_float(h0);
        float l1 = a1 - __uint_as_float(h1);
        L.u[p] = (__float_as_uint(l0) >> 16) | (__float_as_uint(l1) & 0xffff0000u);
    }
    hv = H.v; lv = L.v;
}

// ---------------------------------------------------------------------------
// pre0_gemm_v7: BM=128, BK=32, 4 waves, 2-buffer LDS (48KB -> 3 blocks/CU),
// glds staging + counted vmcnt(18) + raw s_barrier; ALL frag reads via
// inline-asm ds_read_b128 (dodges compiler-inserted vmcnt(0) drain).
// A LDS: per row 128B, 32B-group swizzle: storage group g holds k-group
// g^(r&3) -> global reads stay 32B-monotonic (mergeable), frag b128 reads
// 4-way banked. B traffic halves vs BM=64 (each block reads W once per tile
// for 128 rows instead of 64).
// ---------------------------------------------------------------------------
__global__ __launch_bounds__(256, 3) void pre0_gemm_v7(
    const float* __restrict__ X,
    const unsigned short* __restrict__ Wh, const unsigned short* __restrict__ Wl,
    const float* __restrict__ bias, float* __restrict__ out)
{
    __shared__ float          As[2][4096];      // 32KB: [buf][row*32 + swizzled dword]
    __shared__ unsigned short Bs[2][2][2048];   // 16KB: [buf][h/l][tile-local]

    const int tid  = threadIdx.x;
    const int lane = tid & 63;
    const int wv   = tid >> 6;
    const int fr   = lane & 15;
    const int kg   = lane >> 4;
    const long m0  = (long)blockIdx.x * 128;

    // ---- A staging source geometry: instr i covers rows (wv*32+2i, +1).
    // lane: row = +(lane>>5), storage dword d=lane&31 holds k-dword
    // ((d>>3)^(r&3))*8 + (d&7); r&3 = (2i + (lane>>5)) & 3 -> parity pair.
    const int d     = lane & 31;
    const int rpar  = lane >> 5;
    const int offE  = ((((d >> 3) ^ rpar) * 8) + (d & 7)) * 4;          // i even
    const int offO  = ((((d >> 3) ^ (2 | rpar)) * 8) + (d & 7)) * 4;    // i odd
    const int offEc = offE > 116 ? 116 : offE;                          // tile 33 clamp
    const int offOc = offO > 116 ? 116 : offO;
    const char* Px  = (const char*)X + (m0 + wv * 32 + rpar) * 4344;

    // ---- LDS 32-bit addresses for asm reads (low 32 bits of flat = LDS offset)
    const unsigned aBase = (unsigned)(unsigned long long)(void*)&As[0][0];
    const unsigned bBase = (unsigned)(unsigned long long)(void*)&Bs[0][0][0];
    const unsigned aAddr = aBase + (unsigned)((wv * 32 + fr) * 128 + ((kg ^ (fr & 3)) * 32));
    const unsigned bAddr = bBase + (unsigned)((kg * 64 + fr) * 16);

    f32x4v acc[2][4];
    #pragma unroll
    for (int mf = 0; mf < 2; ++mf)
        #pragma unroll
        for (int nf = 0; nf < 4; ++nf)
            #pragma unroll
            for (int r = 0; r < 4; ++r) acc[mf][nf][r] = 0.0f;

    // fire tile kt into buffer nb: 16 A-glds(size4) + 2 B-glds(size16) = 18
    auto fire = [&](int kt, int nb) {
        const int oE = (kt == 33) ? offEc : offE;
        const int oO = (kt == 33) ? offOc : offO;
        const char* base = Px + (long)kt * 128;
        #pragma unroll
        for (int i2 = 0; i2 < 16; ++i2) {
            const char* s = base + i2 * 8688 + ((i2 & 1) ? oO : oE);
            GLDS(s, &As[nb][(wv * 32 + 2 * i2) * 32], 4);
        }
        GLDS(Wh + (size_t)kt * 2048 + wv * 512 + lane * 8, &Bs[nb][0][wv * 512], 16);
        GLDS(Wl + (size_t)kt * 2048 + wv * 512 + lane * 8, &Bs[nb][1][wv * 512], 16);
    };

#define GEMM_BODY(I, CUR) do {                                                     \
    int ktn = (I) + 1; if (ktn > 33) ktn = 33;                                     \
    fire(ktn, (CUR) ^ 1);                                                          \
    asm volatile("s_waitcnt vmcnt(18)" ::: "memory");  /* F(I) complete */         \
    __builtin_amdgcn_s_barrier();                      /* raw: no drain */         \
    f32x4v a00, a01, a10, a11;                                                     \
    bf16x8 bhv[4], blv[4];                                                         \
    DSR(a00, aAddr, (CUR) * 16384 + 0);                                            \
    DSR(a01, aAddr, (CUR) * 16384 + 16);                                           \
    DSR(a10, aAddr, (CUR) * 16384 + 2048);                                         \
    DSR(a11, aAddr, (CUR) * 16384 + 2064);                                         \
    DSR(bhv[0], bAddr, (CUR) * 8192 + 0);                                          \
    DSR(bhv[1], bAddr, (CUR) * 8192 + 256);                                        \
    DSR(bhv[2], bAddr, (CUR) * 8192 + 512);                                        \
    DSR(bhv[3], bAddr, (CUR) * 8192 + 768);                                        \
    DSR(blv[0], bAddr, (CUR) * 8192 + 4096 + 0);                                   \
    DSR(blv[1], bAddr, (CUR) * 8192 + 4096 + 256);                                 \
    DSR(blv[2], bAddr, (CUR) * 8192 + 4096 + 512);                                 \
    DSR(blv[3], bAddr, (CUR) * 8192 + 4096 + 768);                                 \
    asm volatile("s_waitcnt lgkmcnt(0)" ::: "memory");                             \
    __builtin_amdgcn_s_barrier();      /* all reads done before next fire */       \
    __builtin_amdgcn_sched_barrier(0); /* rule #18: pin MFMA after waits */        \
    float a0[8] = {a00[0],a00[1],a00[2],a00[3],a01[0],a01[1],a01[2],a01[3]};       \
    float a1[8] = {a10[0],a10[1],a10[2],a10[3],a11[0],a11[1],a11[2],a11[3]};       \
    bf16x8 ah0, al0, ah1, al1;                                                     \
    cvt_hilo(a0, ah0, al0);                                                        \
    cvt_hilo(a1, ah1, al1);                                                        \
    _Pragma("unroll")                                                              \
    for (int nf = 0; nf < 4; ++nf) {                                               \
        acc[0][nf] = __builtin_amdgcn_mfma_f32_16x16x32_bf16(ah0, bhv[nf], acc[0][nf], 0, 0, 0); \
        acc[0][nf] = __builtin_amdgcn_mfma_f32_16x16x32_bf16(al0, bhv[nf], acc[0][nf], 0, 0, 0); \
        acc[0][nf] = __builtin_amdgcn_mfma_f32_16x16x32_bf16(ah0, blv[nf], acc[0][nf], 0, 0, 0); \
        acc[1][nf] = __builtin_amdgcn_mfma_f32_16x16x32_bf16(ah1, bhv[nf], acc[1][nf], 0, 0, 0); \
        acc[1][nf] = __builtin_amdgcn_mfma_f32_16x16x32_bf16(al1, bhv[nf], acc[1][nf], 0, 0, 0); \
        acc[1][nf] = __builtin_amdgcn_mfma_f32_16x16x32_bf16(ah1, blv[nf], acc[1][nf], 0, 0, 0); \
    }                                                                              \
} while (0)

    fire(0, 0);                           // prologue
    for (int i = 0; i < KTILES; i += 2) {
        GEMM_BODY(i, 0);
        GEMM_BODY(i + 1, 1);
    }
    asm volatile("s_waitcnt vmcnt(0)" ::: "memory");   // drain trailing dup-fire
#undef GEMM_BODY

    // ---- epilogue: +bias, fp32 store. C/D map: col=lane&15, row=(lane>>4)*4+r
    float bvv[4];
    #pragma unroll
    for (int nf = 0; nf < 4; ++nf) bvv[nf] = bias[nf * 16 + fr];
    #pragma unroll
    for (int mf = 0; mf < 2; ++mf)
        #pragma unroll
        for (int nf = 0; nf < 4; ++nf)
            #pragma unroll
            for (int rr = 0; rr < 4; ++rr) {
                long row = m0 + mf * 16 + wv * 32 + kg * 4 + rr;
                out[row * 64 + nf * 16 + fr] = acc[mf][nf][rr] + bvv[nf];
            }
}

// ---------------------------------------------------------------------------
// mega_scan: 4-wave layer pipeline (unchanged — ~45us).
// ---------------------------------------------------------------------------
__global__ __launch_bounds__(256) void mega_scan(
    const float* __restrict__ pre0, const float* __restrict__ whh0,
    const float* __restrict__ wih1, const float* __restrict__ whh1, const float* __restrict__ b1,
    const float* __restrict__ wih2, const float* __restrict__ whh2, const float* __restrict__ b2,
    const float* __restrict__ wih3, const float* __restrict__ whh3, const float* __restrict__ b3,
    const float* __restrict__ w_fc1, const float* __restrict__ b_fc1,
    const float* __restrict__ w_fc2, const float* __restrict__ b_fc2,
    float* __restrict__ out)
{
    __shared__ float buf[3][T_STEPS][16];

    const int b    = blockIdx.x;
    const int tid  = threadIdx.x;
    const int g    = tid & 63;
    const int wv   = tid >> 6;

    bool sel16 = false, sel32 = false;
#if HAVE_PERMLANE_SWAP
    {
        uv2 q16 = __builtin_amdgcn_permlane16_swap((unsigned)g, (unsigned)g, false, false);
        sel16 = (__builtin_amdgcn_readfirstlane((int)q16[1]) == 16);
        uv2 q32 = __builtin_amdgcn_permlane32_swap((unsigned)g, (unsigned)g, false, false);
        sel32 = (__builtin_amdgcn_readfirstlane((int)q32[1]) == 32);
    }
#endif

    const float* wih = nullptr; const float* whh; const float* bias = nullptr;
    if      (wv == 0) { whh = whh0; }
    else if (wv == 1) { wih = wih1; whh = whh1; bias = b1; }
    else if (wv == 2) { wih = wih2; whh = whh2; bias = b2; }
    else              { wih = wih3; whh = whh3; bias = b3; }

    float whh_r[16];
    #pragma unroll
    for (int q = 0; q < 4; ++q)
        *(float4*)&whh_r[q * 4] = *(const float4*)&whh[g * 16 + q * 4];
    float wih_r[16]; float bg = 0.0f;
    if (wv) {
        #pragma unroll
        for (int q = 0; q < 4; ++q)
            *(float4*)&wih_r[q * 4] = *(const float4*)&wih[g * 16 + q * 4];
        bg = bias[g];
    }

    const float* pb = pre0 + (size_t)b * T_STEPS * 64 + g;
    float pc = 0.0f, p1 = 0.0f, p2 = 0.0f;
    if (wv == 0) { pc = pb[0]; p1 = pb[64]; p2 = pb[128]; }

    float hs[16];
    #pragma unroll
    for (int k = 0; k < 16; ++k) hs[k] = 0.0f;
    float c = 0.0f;

    const int q4 = g >> 4;
    const float escale = (q4 == 2) ? -2.8853900817779268f : -1.4426950408889634f;
    const float am = (q4 == 2) ? 2.0f : 1.0f;
    const float aa = (q4 == 2) ? -1.0f : 0.0f;

    for (int tau = 0; tau < T_STEPS + 3; ++tau) {
        __syncthreads();
        const int t = tau - wv;
        if (t >= 0 && t < T_STEPS) {
            float xr[16];
            if (wv) {
                #pragma unroll
                for (int q = 0; q < 4; ++q)
                    *(float4*)&xr[q * 4] = *(const float4*)&buf[wv - 1][t][q * 4];
            }
            float r0 = fmaf(whh_r[0], hs[0], wv ? bg : pc);
            float r1 = whh_r[1] * hs[1];
            float r2 = whh_r[2] * hs[2];
            float r3 = whh_r[3] * hs[3];
            #pragma unroll
            for (int k = 4; k < 16; k += 4) {
                r0 = fmaf(whh_r[k + 0], hs[k + 0], r0);
                r1 = fmaf(whh_r[k + 1], hs[k + 1], r1);
                r2 = fmaf(whh_r[k + 2], hs[k + 2], r2);
                r3 = fmaf(whh_r[k + 3], hs[k + 3], r3);
            }
            float acc = (r0 + r1) + (r2 + r3);
            if (wv) {
                float p0 = wih_r[0] * xr[0];
                float q1 = wih_r[1] * xr[1];
                float q2 = wih_r[2] * xr[2];
                float q3 = wih_r[3] * xr[3];
                #pragma unroll
                for (int k = 4; k < 16; k += 4) {
                    p0 = fmaf(wih_r[k + 0], xr[k + 0], p0);
                    q1 = fmaf(wih_r[k + 1], xr[k + 1], q1);
                    q2 = fmaf(wih_r[k + 2], xr[k + 2], q2);
                    q3 = fmaf(wih_r[k + 3], xr[k + 3], q3);
                }
                acc += (p0 + q1) + (q2 + q3);
            }
            float e = EXP2F(escale * acc);
            float s = __builtin_amdgcn_rcpf(1.0f + e);
            float a = fmaf(am, s, aa);
#if HAVE_PERMLANE_SWAP
            unsigned au = __float_as_uint(a);
            uv2 r16 = __builtin_amdgcn_permlane16_swap(au, au, false, false);
            uv2 r32 = __builtin_amdgcn_permlane32_swap(au, au, false, false);
            unsigned fvu = sel16 ? r16[1] : r16[0];
            unsigned gvu = sel32 ? r32[1] : r32[0];
            uv2 r48 = __builtin_amdgcn_permlane16_swap(gvu, gvu, false, false);
            unsigned ovu = sel16 ? r48[1] : r48[0];
            float fv = __uint_as_float(fvu);
            float gv = __uint_as_float(gvu);
            float ov = __uint_as_float(ovu);
#else
            float fv = __shfl_xor(a, 16, 64);
            float gv = __shfl_xor(a, 32, 64);
            float ov = __shfl_xor(a, 48, 64);
#endif
            c = fmaf(fv, c, a * gv);
            float e2 = EXP2F(-2.8853900817779268f * c);
            float s2 = __builtin_amdgcn_rcpf(1.0f + e2);
            float hn = fmaf(ov + ov, s2, -ov);
            if (wv < 3 && g < 16) buf[wv][t][g] = hn;
            #pragma unroll
            for (int k = 0; k < 16; ++k) hs[k] = rl_f(hn, k);
            if (wv == 0) {
                pc = p1; p1 = p2;
                int tn = t + 3; tn = tn < T_STEPS ? tn : T_STEPS - 1;
                p2 = pb[(size_t)tn * 64];
            }
        }
    }

    if (wv == 3 && g < 16) {
        float a1 = b_fc1[g];
        #pragma unroll
        for (int k = 0; k < 16; ++k) a1 = fmaf(w_fc1[g * 16 + k], hs[k], a1);
        a1 = fmaxf(a1, 0.0f);
        float h1[16];
        #pragma unroll
        for (int k = 0; k < 16; ++k) h1[k] = rl_f(a1, k);
        float lg = -3.0e38f;
        if (g < 15) {
            lg = b_fc2[g];
            #pragma unroll
            for (int k = 0; k < 16; ++k) lg = fmaf(w_fc2[g * 16 + k], h1[k], lg);
        }
        float mx = lg;
        #pragma unroll
        for (int dd = 8; dd >= 1; dd >>= 1) mx = fmaxf(mx, __shfl_xor(mx, dd, 16));
        float ev = (g < 15) ? EXP2F(1.4426950408889634f * (lg - mx)) : 0.0f;
        float sm = ev;
        #pragma unroll
        for (int dd = 8; dd >= 1; dd >>= 1) sm += __shfl_xor(sm, dd, 16);
        if (g < 15) out[b * 15 + g] = ev * __builtin_amdgcn_rcpf(sm);
    }
}

extern "C" void kernel_launch(void* const* d_in, const int* in_sizes, int n_in,
                              void* d_out, int out_size, void* d_ws, size_t ws_size,
                              hipStream_t stream) {
    const float* x    = (const float*)d_in[0];
    const float* wih0 = (const float*)d_in[1];
    const float* whh0 = (const float*)d_in[2];
    const float* b0   = (const float*)d_in[3];
    const float* wih1 = (const float*)d_in[4];
    const float* whh1 = (const float*)d_in[5];
    const float* b1   = (const float*)d_in[6];
    const float* wih2 = (const float*)d_in[7];
    const float* whh2 = (const float*)d_in[8];
    const float* b2   = (const float*)d_in[9];
    const float* wih3 = (const float*)d_in[10];
    const float* whh3 = (const float*)d_in[11];
    const float* b3   = (const float*)d_in[12];
    const float* wfc1 = (const float*)d_in[13];
    const float* bfc1 = (const float*)d_in[14];
    const float* wfc2 = (const float*)d_in[15];
    const float* bfc2 = (const float*)d_in[16];

    float* pre0 = (float*)d_ws;                                       // 13,107,200 B
    unsigned short* Wh = (unsigned short*)((char*)d_ws + 13107200);   // 139,264 B
    unsigned short* Wl = (unsigned short*)((char*)d_ws + 13107200 + 139264);

    prepack_w<<<dim3((KTILES * 4 * 64 * 8 + 255) / 256), dim3(256), 0, stream>>>(wih0, Wh, Wl);
    pre0_gemm_v7<<<dim3(M_TOTAL / 128), dim3(256), 0, stream>>>(x, Wh, Wl, b0, pre0);
    mega_scan<<<dim3(256), dim3(256), 0, stream>>>(pre0, whh0,
        wih1, whh1, b1, wih2, whh2, b2, wih3, whh3, b3,
        wfc1, bfc1, wfc2, bfc2, (float*)d_out);
}